// Round 16
// baseline (85.676 us; speedup 1.0000x reference)
//
#include <hip/hip_runtime.h>
#include <stdint.h>
#include <stddef.h>

typedef int   v4i __attribute__((ext_vector_type(4)));
typedef float v4f __attribute__((ext_vector_type(4)));

#define M_DIM 32768
#define N_DIM 1024
#define K_DIM 1024
#define BM 32            // rows per block; block owns [32][1024] of out
#define KSTEPS 16        // K=1024 / 64

// ---------------- pass 0: repack W int32 [N][K] -> fragment-linear int8 -----
// (R12-verified layout) Frag id f = ((p*8 + wv)*16 + ks)*2 + j ;
// p = n-pass (256 cols), wv = wave, j = 16-col subfrag. Lane ln dword dw:
// W[n = p*256 + wv*32 + j*16 + (ln&15)][k = ks*64 + (ln>>4)*16 + dw*4 ..+4].
__global__ __launch_bounds__(256)
void repack_w_kernel(const int* __restrict__ w32, int* __restrict__ wf)
{
    const int i  = blockIdx.x * 256 + threadIdx.x;   // dword index, < 262144
    const int f  = i >> 8;            // fragment id 0..1023
    const int r  = i & 255;
    const int ln = r >> 2;            // lane 0..63
    const int dw = r & 3;             // dword within 16B
    const int j  = f & 1;
    const int ks = (f >> 1) & 15;
    const int wv = (f >> 5) & 7;
    const int p  = f >> 8;
    const int n  = p * 256 + wv * 32 + j * 16 + (ln & 15);
    const int k  = ks * 64 + (ln >> 4) * 16 + dw * 4;
    const v4i v  = *(const v4i*)&w32[(size_t)n * K_DIM + k];
    wf[i] = (v[0] & 255) | ((v[1] & 255) << 8) |
            ((v[2] & 255) << 16) | ((v[3] & 255) << 24);
}

// ---------------- fused: quantize x -> LDS, then int8 GEMM + dequant --------
// HIGH-OCCUPANCY tier: BM=32, LDS 32 KiB, <=64 regs/wave enforced by
// __launch_bounds__(512, 8) -> 4 blocks/CU, 32 waves/CU (2x the R8 TLP).
// 8 waves; per n-pass (256 cols) each wave owns [32m][32n] = 2x2 of
// 16x16x64 i8 MFMA (acc 16 AGPR); 4 passes cover N=1024.
__global__ __launch_bounds__(512, 8)
void fused_kernel(const float* __restrict__ x,
                  const signed char* __restrict__ Wf,
                  const float* __restrict__ wscale,
                  const float* __restrict__ iscale_p,
                  const float* __restrict__ bias,
                  float* __restrict__ out)
{
    __shared__ signed char lA[BM * K_DIM];   // 32 KiB, swizzled col^((row&7)<<4)

    const int mrow0 = blockIdx.x * BM;
    const int t  = threadIdx.x;
    const int wv = t >> 6;
    const int ln = t & 63;

    // ---- phase 1: load fp32 slab, quantize, swizzled LDS write (R8 style) --
    {
        const float inv = 1.0f / *iscale_p;
        const int colf = (t & 255) * 4;          // int8/float column
        const int rsub = t >> 8;                 // 0..1
        for (int j = 0; j < 16; ++j) {
            const int row = j * 2 + rsub;
            const v4f v = *(const v4f*)&x[(size_t)(mrow0 + row) * K_DIM + colf];
            int r = 0;
            #pragma unroll
            for (int e = 0; e < 4; ++e) {
                float q = rintf(v[e] * inv);     // round-half-even like jnp
                q = fminf(127.f, fmaxf(-128.f, q));
                r |= ((int)q & 255) << (8 * e);
            }
            *(int*)&lA[row * K_DIM + (colf ^ ((row & 7) << 4))] = r;
        }
    }
    __syncthreads();   // the only barrier: LDS A-tile complete

    const int lr = ln & 15;
    const int kh = (ln >> 4) * 16;
    const float is = *iscale_p;

    for (int p = 0; p < 4; ++p) {
        v4i acc[2][2] = {};
        #pragma unroll 4
        for (int ks = 0; ks < KSTEPS; ++ks) {
            v4i aF[2], bF[2];
            #pragma unroll
            for (int i = 0; i < 2; ++i) {
                const int row = i * 16 + lr;
                aF[i] = *(const v4i*)&lA[row * K_DIM +
                                         ((ks * 64 + kh) ^ ((row & 7) << 4))];
            }
            const size_t fbase = ((size_t)(p * 8 + wv) * 16 + ks) * 2;
            #pragma unroll
            for (int j = 0; j < 2; ++j)
                bF[j] = *(const v4i*)&Wf[(fbase + j) * 1024 + ln * 16];
            #pragma unroll
            for (int i = 0; i < 2; ++i)
                #pragma unroll
                for (int j = 0; j < 2; ++j)
                    acc[i][j] = __builtin_amdgcn_mfma_i32_16x16x64_i8(
                                    aF[i], bF[j], acc[i][j], 0, 0, 0);
        }
        // epilogue for this n-pass: C/D col = ln&15, row = (ln>>4)*4 + r
        const int c00 = p * 256 + wv * 32;
        #pragma unroll
        for (int j = 0; j < 2; ++j) {
            const int col = c00 + j * 16 + lr;
            const float sc = wscale[col] * is;
            const float bv = bias[col];
            #pragma unroll
            for (int i = 0; i < 2; ++i) {
                const int rowb = mrow0 + i * 16 + ((ln >> 4) << 2);
                #pragma unroll
                for (int r = 0; r < 4; ++r)
                    out[(size_t)(rowb + r) * N_DIM + col] =
                        (float)acc[i][j][r] * sc + bv;
            }
        }
    }
}

extern "C" void kernel_launch(void* const* d_in, const int* in_sizes, int n_in,
                              void* d_out, int out_size, void* d_ws, size_t ws_size,
                              hipStream_t stream)
{
    const float* x       = (const float*)d_in[0];
    const int*   w32     = (const int*)d_in[1];   // int8 weight stored as int32 [N][K]
    const float* wscale  = (const float*)d_in[2];
    const float* iscale  = (const float*)d_in[3];
    const float* bias    = (const float*)d_in[4];
    float* out           = (float*)d_out;

    signed char* wf = (signed char*)d_ws;         // 1 MiB fragment-linear W

    repack_w_kernel<<<(N_DIM * K_DIM / 4) / 256, 256, 0, stream>>>(w32, (int*)wf);

    fused_kernel<<<M_DIM / BM, 512, 0, stream>>>(x, wf, wscale, iscale, bias, out);
}

// Round 17
// 69.762 us; speedup vs baseline: 1.2281x; 1.2281x over previous
//
#include <hip/hip_runtime.h>
#include <stdint.h>
#include <stddef.h>

typedef int   v4i __attribute__((ext_vector_type(4)));
typedef float v4f __attribute__((ext_vector_type(4)));

#define M_DIM 32768
#define N_DIM 1024
#define K_DIM 1024
#define BM 64            // rows per block; block owns [64][1024] of out
#define KSTEPS 16        // K=1024 / 64

// ---------------- pass 0: repack W int32 [N][K] -> fragment-linear int8 -----
// Frag id f = ((np*8 + wv)*16 + ks)*4 + j ; np=n-pass(512 cols), wv=wave,
// j = 16-col subfrag. Lane ln dword dw holds
// W[n = np*512 + wv*64 + j*16 + (ln&15)][k = ks*64 + (ln>>4)*16 + dw*4 ..+4].
__global__ __launch_bounds__(256)
void repack_w_kernel(const int* __restrict__ w32, int* __restrict__ wf)
{
    const int i  = blockIdx.x * 256 + threadIdx.x;   // dword index, < 262144
    const int f  = i >> 8;            // fragment id 0..1023
    const int r  = i & 255;
    const int ln = r >> 2;            // lane 0..63
    const int dw = r & 3;             // dword within 16B
    const int j  = f & 3;
    const int ks = (f >> 2) & 15;
    const int wv = (f >> 6) & 7;
    const int np = f >> 9;
    const int n  = np * 512 + wv * 64 + j * 16 + (ln & 15);
    const int k  = ks * 64 + (ln >> 4) * 16 + dw * 4;
    const v4i v  = *(const v4i*)&w32[(size_t)n * K_DIM + k];
    wf[i] = (v[0] & 255) | ((v[1] & 255) << 8) |
            ((v[2] & 255) << 16) | ((v[3] & 255) << 24);
}

// ---------------- fused: quantize x -> LDS, then int8 GEMM + dequant --------
// 512 threads = 8 waves. Each wave owns [64 rows][64 cols] per n-pass:
// 4x4 of 16x16x64 i8 MFMA (acc 64 AGPR), 2 passes cover N=1024.
// MEASURED OPTIMUM (R8: 69.6us, R15: 69.2us). The register budget sits
// EXACTLY at the 128/wave cap of (512,4): acc 64 + operands/addressing ~64.
// Fully-mapped dead ends: BM=32 high-occupancy (R16: +16us, 2x W-traffic),
// cross-kstep B prefetch (R10: spill, 4x), 32x32 MFMA (R13: store inflation),
// nt-stores (R14: -12%), store-swap/quant-batch/K-slice (R9/R11/R12: neutral),
// unfused 2-kernel structures (R2/R4/R6: 85-91us).
__global__ __launch_bounds__(512, 4)
void fused_kernel(const float* __restrict__ x,
                  const signed char* __restrict__ Wf,
                  const float* __restrict__ wscale,
                  const float* __restrict__ iscale_p,
                  const float* __restrict__ bias,
                  float* __restrict__ out)
{
    __shared__ signed char lA[BM * K_DIM];   // 64 KiB, swizzled col^((row&7)<<4)

    const int mrow0 = blockIdx.x * BM;
    const int t  = threadIdx.x;
    const int wv = t >> 6;
    const int ln = t & 63;

    // ---- phase 1: load fp32 slab, quantize, swizzled LDS write ----
    {
        const float inv = 1.0f / *iscale_p;
        const int colf = (t & 255) * 4;          // int8/float column
        const int rsub = t >> 8;                 // 0..1
        for (int j = 0; j < 32; ++j) {
            const int row = j * 2 + rsub;
            const v4f v = *(const v4f*)&x[(size_t)(mrow0 + row) * K_DIM + colf];
            int r = 0;
            #pragma unroll
            for (int e = 0; e < 4; ++e) {
                float q = rintf(v[e] * inv);     // round-half-even like jnp
                q = fminf(127.f, fmaxf(-128.f, q));
                r |= ((int)q & 255) << (8 * e);
            }
            *(int*)&lA[row * K_DIM + (colf ^ ((row & 7) << 4))] = r;
        }
    }
    __syncthreads();   // the only barrier: LDS A-tile complete

    const int lr = ln & 15;
    const int kh = (ln >> 4) * 16;
    const float is = *iscale_p;

    for (int np = 0; np < 2; ++np) {
        v4i acc[4][4] = {};
        #pragma unroll 4
        for (int ks = 0; ks < KSTEPS; ++ks) {
            v4i aF[4], bF[4];
            #pragma unroll
            for (int i = 0; i < 4; ++i) {
                const int row = i * 16 + lr;
                aF[i] = *(const v4i*)&lA[row * K_DIM +
                                         ((ks * 64 + kh) ^ ((row & 7) << 4))];
            }
            const size_t fbase = ((size_t)(np * 8 + wv) * 16 + ks) * 4;
            #pragma unroll
            for (int j = 0; j < 4; ++j)
                bF[j] = *(const v4i*)&Wf[(fbase + j) * 1024 + ln * 16];
            #pragma unroll
            for (int i = 0; i < 4; ++i)
                #pragma unroll
                for (int j = 0; j < 4; ++j)
                    acc[i][j] = __builtin_amdgcn_mfma_i32_16x16x64_i8(
                                    aF[i], bF[j], acc[i][j], 0, 0, 0);
        }
        // epilogue for this n-pass: C/D col = ln&15, row = (ln>>4)*4 + r
        const int c00 = np * 512 + wv * 64;
        #pragma unroll
        for (int j = 0; j < 4; ++j) {
            const int col = c00 + j * 16 + lr;
            const float sc = wscale[col] * is;
            const float bv = bias[col];
            #pragma unroll
            for (int i = 0; i < 4; ++i) {
                const int rowb = mrow0 + i * 16 + ((ln >> 4) << 2);
                #pragma unroll
                for (int r = 0; r < 4; ++r)
                    out[(size_t)(rowb + r) * N_DIM + col] =
                        (float)acc[i][j][r] * sc + bv;
            }
        }
    }
}

extern "C" void kernel_launch(void* const* d_in, const int* in_sizes, int n_in,
                              void* d_out, int out_size, void* d_ws, size_t ws_size,
                              hipStream_t stream)
{
    const float* x       = (const float*)d_in[0];
    const int*   w32     = (const int*)d_in[1];   // int8 weight stored as int32 [N][K]
    const float* wscale  = (const float*)d_in[2];
    const float* iscale  = (const float*)d_in[3];
    const float* bias    = (const float*)d_in[4];
    float* out           = (float*)d_out;

    signed char* wf = (signed char*)d_ws;         // 1 MiB fragment-linear W

    repack_w_kernel<<<(N_DIM * K_DIM / 4) / 256, 256, 0, stream>>>(w32, (int*)wf);

    fused_kernel<<<M_DIM / BM, 512, 0, stream>>>(x, wf, wscale, iscale, bias, out);
}